// Round 1
// baseline (148.710 us; speedup 1.0000x reference)
//
#include <hip/hip_runtime.h>

// CharacteristicLineEncoder: B=4096, DIM=3, L=300, S=60, P=5, E=128
// out[b,s,e] = sum_p W_lr[s,p]*relu(W_le[e,:]·x[b,:,s*5+p] + b_le[e]) + b_lr[s]
//            + relu( sum_l W_gn[l]*relu(W_ge[e,:]·x[b,:,l] + b_ge[e]) + b_gn )

#define Bv 4096
#define Lv 300
#define Sv 60
#define Ev 128
#define Pv 5

__global__ __launch_bounds__(128) void cle_kernel(
    const float* __restrict__ x,     // [B,3,L]
    const float* __restrict__ W_le,  // [E,3]
    const float* __restrict__ b_le,  // [E]
    const float* __restrict__ W_lr,  // [S,P] flat = [l]
    const float* __restrict__ b_lr,  // [S]
    const float* __restrict__ W_ge,  // [E,3]
    const float* __restrict__ b_ge,  // [E]
    const float* __restrict__ W_gn,  // [L]
    const float* __restrict__ b_gn,  // [1]
    float* __restrict__ out)         // [B,S,E]
{
    const int e = threadIdx.x;   // 0..127  (one embedding channel per lane)
    const int b = blockIdx.x;    // one batch element per block

    const float* xb  = x + (size_t)b * (3 * Lv);
    const float* x0p = xb;
    const float* x1p = xb + Lv;
    const float* x2p = xb + 2 * Lv;

    // per-thread (per-e) weights
    const float wl0 = W_le[e * 3 + 0], wl1 = W_le[e * 3 + 1], wl2 = W_le[e * 3 + 2];
    const float bl  = b_le[e];
    const float wg0 = W_ge[e * 3 + 0], wg1 = W_ge[e * 3 + 1], wg2 = W_ge[e * 3 + 2];
    const float bg  = b_ge[e];

    // ---- pass 1: global branch, reduce over all L positions ----
    float gacc = 0.0f;
#pragma unroll 4
    for (int l = 0; l < Lv; ++l) {
        const float xx0 = x0p[l], xx1 = x1p[l], xx2 = x2p[l];   // wave-uniform
        float ge = fmaf(wg2, xx2, fmaf(wg1, xx1, fmaf(wg0, xx0, bg)));
        gacc = fmaf(W_gn[l], fmaxf(ge, 0.0f), gacc);
    }
    const float gf = fmaxf(gacc + b_gn[0], 0.0f);

    // ---- pass 2: local branch, one output row per region s ----
    float* ob = out + (size_t)b * (Sv * Ev) + e;
#pragma unroll 2
    for (int s = 0; s < Sv; ++s) {
        float acc = b_lr[s];
#pragma unroll
        for (int p = 0; p < Pv; ++p) {
            const int l = s * Pv + p;
            const float xx0 = x0p[l], xx1 = x1p[l], xx2 = x2p[l];
            float le = fmaf(wl2, xx2, fmaf(wl1, xx1, fmaf(wl0, xx0, bl)));
            acc = fmaf(W_lr[l], fmaxf(le, 0.0f), acc);
        }
        ob[(size_t)s * Ev] = acc + gf;
    }
}

extern "C" void kernel_launch(void* const* d_in, const int* in_sizes, int n_in,
                              void* d_out, int out_size, void* d_ws, size_t ws_size,
                              hipStream_t stream) {
    const float* x    = (const float*)d_in[0];
    const float* W_le = (const float*)d_in[1];
    const float* b_le = (const float*)d_in[2];
    const float* W_lr = (const float*)d_in[3];
    const float* b_lr = (const float*)d_in[4];
    const float* W_ge = (const float*)d_in[5];
    const float* b_ge = (const float*)d_in[6];
    const float* W_gn = (const float*)d_in[7];
    const float* b_gn = (const float*)d_in[8];
    float* out = (float*)d_out;

    cle_kernel<<<Bv, Ev, 0, stream>>>(x, W_le, b_le, W_lr, b_lr,
                                      W_ge, b_ge, W_gn, b_gn, out);
}

// Round 2
// 51.973 us; speedup vs baseline: 2.8613x; 2.8613x over previous
//
#include <hip/hip_runtime.h>

// CharacteristicLineEncoder: B=4096, DIM=3, L=300, S=60, P=5, E=128
// out[b,s,e] = sum_p W_lr[s,p]*relu(W_le[e,:]·x[b,:,5s+p] + b_le[e]) + b_lr[s]
//            + relu( sum_l W_gn[l]*relu(W_ge[e,:]·x[b,:,l] + b_ge[e]) + b_gn )

#define Bv 4096
#define Lv 300
#define Sv 60
#define Ev 128

#define RELU(v) fmaxf((v), 0.0f)

__global__ __launch_bounds__(128) void cle_kernel(
    const float* __restrict__ x,     // [B,3,L]
    const float* __restrict__ W_le,  // [E,3]
    const float* __restrict__ b_le,  // [E]
    const float* __restrict__ W_lr,  // [S,P] flat [300]
    const float* __restrict__ b_lr,  // [S]
    const float* __restrict__ W_ge,  // [E,3]
    const float* __restrict__ b_ge,  // [E]
    const float* __restrict__ W_gn,  // [L]
    const float* __restrict__ b_gn,  // [1]
    float* __restrict__ out)         // [B,S,E]
{
    const int e = threadIdx.x;   // 0..127, one embedding channel per lane
    const int b = blockIdx.x;    // one batch element per block

    __shared__ __align__(16) float sx[900];     // x[b] : [3][300]
    __shared__ __align__(16) float swgn[300];
    __shared__ __align__(16) float swlr[300];
    __shared__ __align__(16) float sblr[60];

    // ---- stage: coalesced float4 loads ----
    {
        const float4* xg4 = (const float4*)(x + (size_t)b * 900);  // 225 quads
        float4* sx4 = (float4*)sx;
        for (int i = e; i < 225; i += 128) sx4[i] = xg4[i];
        if (e < 75) {
            ((float4*)swgn)[e] = ((const float4*)W_gn)[e];
            ((float4*)swlr)[e] = ((const float4*)W_lr)[e];
        }
        if (e < 15) ((float4*)sblr)[e] = ((const float4*)b_lr)[e];
    }

    // per-thread (per-e) weights — lanes differ, tiny & L2-hot
    const float wl0 = W_le[e * 3 + 0], wl1 = W_le[e * 3 + 1], wl2 = W_le[e * 3 + 2];
    const float bl  = b_le[e];
    const float wg0 = W_ge[e * 3 + 0], wg1 = W_ge[e * 3 + 1], wg2 = W_ge[e * 3 + 2];
    const float bg  = b_ge[e];
    const float bgn = b_gn[0];

    __syncthreads();

    const float4* sx0q  = (const float4*)sx;          // 75 quads, channel 0
    const float4* sx1q  = (const float4*)(sx + 300);  // channel 1
    const float4* sx2q  = (const float4*)(sx + 600);  // channel 2
    const float4* swgnq = (const float4*)swgn;
    const float4* swlrq = (const float4*)swlr;
    const float4* sblrq = (const float4*)sblr;

    // ---- pass 1: global branch, 4 l-positions per iter, 4 indep accumulators ----
    float g0 = 0.f, g1 = 0.f, g2 = 0.f, g3 = 0.f;
#define GEc(cmp) RELU(fmaf(wg2, c2.cmp, fmaf(wg1, c1.cmp, fmaf(wg0, c0.cmp, bg))))
#pragma unroll 5
    for (int q = 0; q < 75; ++q) {
        const float4 c0 = sx0q[q], c1 = sx1q[q], c2 = sx2q[q], w4 = swgnq[q];
        g0 = fmaf(w4.x, GEc(x), g0);
        g1 = fmaf(w4.y, GEc(y), g1);
        g2 = fmaf(w4.z, GEc(z), g2);
        g3 = fmaf(w4.w, GEc(w), g3);
    }
    const float gf = RELU(((g0 + g1) + (g2 + g3)) + bgn);

    // ---- pass 2: local branch, 4 regions (20 l = 5 quads) per group ----
    float* ob = out + (size_t)b * (Sv * Ev) + e;

#define LEc(cmp) RELU(fmaf(wl2, c2.cmp, fmaf(wl1, c1.cmp, fmaf(wl0, c0.cmp, bl))))
#define DOQ(qi, A0, A1, A2, A3)                                                  \
    {                                                                            \
        const float4 c0 = sx0q[bq5 + (qi)], c1 = sx1q[bq5 + (qi)],               \
                     c2 = sx2q[bq5 + (qi)], w4 = swlrq[bq5 + (qi)];              \
        A0 = fmaf(w4.x, LEc(x), A0);                                             \
        A1 = fmaf(w4.y, LEc(y), A1);                                             \
        A2 = fmaf(w4.z, LEc(z), A2);                                             \
        A3 = fmaf(w4.w, LEc(w), A3);                                             \
    }

    for (int g = 0; g < 15; ++g) {
        const int bq5 = g * 5;
        const float4 bl4 = sblrq[g];
        float acc0 = bl4.x, acc1 = bl4.y, acc2 = bl4.z, acc3 = bl4.w;
        // element t = 4*qi + j  (l = 20g + t), region r = t/5
        DOQ(0, acc0, acc0, acc0, acc0)   // t 0..3   -> r0
        DOQ(1, acc0, acc1, acc1, acc1)   // t 4..7   -> r0,r1,r1,r1
        DOQ(2, acc1, acc1, acc2, acc2)   // t 8..11  -> r1,r1,r2,r2
        DOQ(3, acc2, acc2, acc2, acc3)   // t 12..15 -> r2,r2,r2,r3
        DOQ(4, acc3, acc3, acc3, acc3)   // t 16..19 -> r3
        float* og = ob + (size_t)g * (4 * Ev);
        og[0 * Ev] = acc0 + gf;
        og[1 * Ev] = acc1 + gf;
        og[2 * Ev] = acc2 + gf;
        og[3 * Ev] = acc3 + gf;
    }
}

extern "C" void kernel_launch(void* const* d_in, const int* in_sizes, int n_in,
                              void* d_out, int out_size, void* d_ws, size_t ws_size,
                              hipStream_t stream) {
    const float* x    = (const float*)d_in[0];
    const float* W_le = (const float*)d_in[1];
    const float* b_le = (const float*)d_in[2];
    const float* W_lr = (const float*)d_in[3];
    const float* b_lr = (const float*)d_in[4];
    const float* W_ge = (const float*)d_in[5];
    const float* b_ge = (const float*)d_in[6];
    const float* W_gn = (const float*)d_in[7];
    const float* b_gn = (const float*)d_in[8];
    float* out = (float*)d_out;

    cle_kernel<<<Bv, Ev, 0, stream>>>(x, W_le, b_le, W_lr, b_lr,
                                      W_ge, b_ge, W_gn, b_gn, out);
}

// Round 3
// 50.738 us; speedup vs baseline: 2.9309x; 1.0243x over previous
//
#include <hip/hip_runtime.h>

// CharacteristicLineEncoder: B=4096, DIM=3, L=300, S=60, P=5, E=128
// out[b,s,e] = sum_p W_lr[s,p]*relu(W_le[e,:]·x[b,:,5s+p] + b_le[e]) + b_lr[s]
//            + relu( sum_l W_gn[l]*relu(W_ge[e,:]·x[b,:,l] + b_ge[e]) + b_gn )
//
// Single fused sweep over l. x staged in LDS (broadcast ds_read_b128, the
// irreducible 225 reads/wave); all l-indexed weights read via the SCALAR
// path (wave-uniform addresses -> s_load, constant-cache hot). 60 local
// accumulators kept in registers (statically indexed, fully unrolled).

#define Bv 4096
#define Lv 300
#define Sv 60
#define Ev 128

#define RELU(v) fmaxf((v), 0.0f)

__global__ __launch_bounds__(128) void cle_kernel(
    const float* __restrict__ x,     // [B,3,L]
    const float* __restrict__ W_le,  // [E,3]
    const float* __restrict__ b_le,  // [E]
    const float* __restrict__ W_lr,  // [S,P] flat [300]
    const float* __restrict__ b_lr,  // [S]
    const float* __restrict__ W_ge,  // [E,3]
    const float* __restrict__ b_ge,  // [E]
    const float* __restrict__ W_gn,  // [L]
    const float* __restrict__ b_gn,  // [1]
    float* __restrict__ out)         // [B,S,E]
{
    const int e = threadIdx.x;   // 0..127, one embedding channel per lane
    const int b = blockIdx.x;    // one batch element per block

    // x[b] as quads: channel c, quad q at sx4[c*75 + q]
    __shared__ __align__(16) float4 sx4[225];

    {
        const float4* xg4 = (const float4*)(x + (size_t)b * 900);
        for (int i = e; i < 225; i += 128) sx4[i] = xg4[i];
    }

    // per-lane (per-e) weights
    const float wl0 = W_le[e * 3 + 0], wl1 = W_le[e * 3 + 1], wl2 = W_le[e * 3 + 2];
    const float bl  = b_le[e];
    const float wg0 = W_ge[e * 3 + 0], wg1 = W_ge[e * 3 + 1], wg2 = W_ge[e * 3 + 2];
    const float bg  = b_ge[e];
    const float bgn = b_gn[0];

    __syncthreads();

    float g0 = 0.f, g1 = 0.f, g2 = 0.f, g3 = 0.f;
    float la[60];
#pragma unroll
    for (int i = 0; i < 60; ++i) la[i] = 0.0f;

#define GEq(cmp) RELU(fmaf(wg2, c2.cmp, fmaf(wg1, c1.cmp, fmaf(wg0, c0.cmp, bg))))
#define LEq(cmp) RELU(fmaf(wl2, c2.cmp, fmaf(wl1, c1.cmp, fmaf(wl0, c0.cmp, bl))))
    // One quad = 4 l-positions: global-branch accumulate + local-branch
    // accumulate into the statically-chosen region accumulators A0..A3.
#define DOQ(qi, A0, A1, A2, A3)                                            \
    {                                                                      \
        const int qq = q0 + (qi);                                          \
        const int l4 = qq * 4;                                             \
        const float4 c0 = sx4[qq], c1 = sx4[75 + qq], c2 = sx4[150 + qq];  \
        g0 = fmaf(W_gn[l4 + 0], GEq(x), g0);                               \
        g1 = fmaf(W_gn[l4 + 1], GEq(y), g1);                               \
        g2 = fmaf(W_gn[l4 + 2], GEq(z), g2);                               \
        g3 = fmaf(W_gn[l4 + 3], GEq(w), g3);                               \
        A0 = fmaf(W_lr[l4 + 0], LEq(x), A0);                               \
        A1 = fmaf(W_lr[l4 + 1], LEq(y), A1);                               \
        A2 = fmaf(W_lr[l4 + 2], LEq(z), A2);                               \
        A3 = fmaf(W_lr[l4 + 3], LEq(w), A3);                               \
    }

#pragma unroll
    for (int g = 0; g < 15; ++g) {
        const int q0 = g * 5;
        const int r = 4 * g;
        // element t = 4*qi + component (l = 20g + t), region = 4g + t/5
        DOQ(0, la[r + 0], la[r + 0], la[r + 0], la[r + 0])  // t 0..3
        DOQ(1, la[r + 0], la[r + 1], la[r + 1], la[r + 1])  // t 4..7
        DOQ(2, la[r + 1], la[r + 1], la[r + 2], la[r + 2])  // t 8..11
        DOQ(3, la[r + 2], la[r + 2], la[r + 2], la[r + 3])  // t 12..15
        DOQ(4, la[r + 3], la[r + 3], la[r + 3], la[r + 3])  // t 16..19
    }

    const float gf = RELU(((g0 + g1) + (g2 + g3)) + bgn);

    float* ob = out + (size_t)b * (Sv * Ev) + e;
#pragma unroll
    for (int s = 0; s < 60; ++s) {
        ob[(size_t)s * Ev] = (la[s] + gf) + b_lr[s];   // b_lr[s] is SGPR
    }
}

extern "C" void kernel_launch(void* const* d_in, const int* in_sizes, int n_in,
                              void* d_out, int out_size, void* d_ws, size_t ws_size,
                              hipStream_t stream) {
    const float* x    = (const float*)d_in[0];
    const float* W_le = (const float*)d_in[1];
    const float* b_le = (const float*)d_in[2];
    const float* W_lr = (const float*)d_in[3];
    const float* b_lr = (const float*)d_in[4];
    const float* W_ge = (const float*)d_in[5];
    const float* b_ge = (const float*)d_in[6];
    const float* W_gn = (const float*)d_in[7];
    const float* b_gn = (const float*)d_in[8];
    float* out = (float*)d_out;

    cle_kernel<<<Bv, Ev, 0, stream>>>(x, W_le, b_le, W_lr, b_lr,
                                      W_ge, b_ge, W_gn, b_gn, out);
}